// Round 17
// baseline (1852.724 us; speedup 1.0000x reference)
//
#include <hip/hip_runtime.h>
#include <hip/hip_bf16.h>
#include <math.h>

// NeighborGatedAttention, bf16-MFMA, DUAL-b (R16 base + T2 XOR swizzle).
// L=2, B=8192, NNEI=128, EMB=HID=128. One block (512 thr = 8 waves), TWO b's.
// R16 (1660us): R13 + layer-0 x' bf16 stash in bufB (layer-1 xf from LDS).
// NEW: all big-buffer accesses go through swz(row,col)=row*ROWP+(col^((row&7)<<4))
// (32B-granule XOR, bijective within row). Fixes the 8-way bank-conflict on
// every column-slice fragment read (row=base+lc, ROWP=136 -> stride 4 banks):
// start banks (4lc)%32 8-way -> (4lc+8(lc&7))%32 2-way (free, m136).
// Register-neutral, bit-identical numerics.
// LDS 154.6KB, 1 block/CU, 2 waves/SIMD.

typedef __attribute__((ext_vector_type(8))) short bf16x8; // 8 bf16 = 4 VGPR
typedef __attribute__((ext_vector_type(4))) float f32x4;
typedef unsigned short ushort_t;

constexpr float F_SHIFT   = 20.0f;
constexpr float F_SCALING = 0.08838834764831845f; // 128^-0.5
constexpr float F_LNEPS   = 1e-5f;

constexpr int ROWP = 136;                 // ushort row pitch (272B)
constexpr int BUF_US = 128 * ROWP;        // 17408 ushorts per buffer
constexpr size_t WTI_ELEMS = 2 * 384 * 128;
constexpr size_t WTO_ELEMS = 2 * 128 * 128;
constexpr int TAB_F = 1920;               // per-b table floats
constexpr int LDS_BYTES = 4 * BUF_US * 2 + 2 * TAB_F * 4; // 154624

#define MFMA(a, b, c) __builtin_amdgcn_mfma_f32_16x16x32_bf16(a, b, c, 0, 0, 0)

// T2 swizzle: XOR 32B granule index with row&7. Bijective within row
// (col < 128 data ushorts, XOR bits [4..6]); keeps 16B/8B alignment since
// b128 cols are multiples of 8 and ushort4 cols multiples of 4.
__device__ __forceinline__ int swz(int row, int col) {
  return row * ROWP + (col ^ ((row & 7) << 4));
}

__device__ __forceinline__ ushort_t f2bf(float f) {
  __hip_bfloat16 h = __float2bfloat16(f);
  return *reinterpret_cast<ushort_t*>(&h);
}
__device__ __forceinline__ ushort4 pack4(float a, float b, float c, float d) {
  return make_ushort4(f2bf(a), f2bf(b), f2bf(c), f2bf(d));
}

// A/B fragment from pre-transposed bf16 weights (WS) or fp32 gather fallback.
template <bool WS>
__device__ __forceinline__ bf16x8 wt_frag(const ushort_t* __restrict__ wt,
                                          const float* __restrict__ W,
                                          int r, int c, int ldW) {
  if constexpr (WS) {
    return *(const bf16x8*)(wt + r * 128 + c);
  } else {
    bf16x8 f;
#pragma unroll
    for (int j = 0; j < 8; ++j) f[j] = (short)f2bf(W[(size_t)(c + j) * ldW + r]);
    return f;
  }
}

__global__ void prep_weights(const float* __restrict__ Win, const float* __restrict__ Wout,
                             ushort_t* __restrict__ wtI, ushort_t* __restrict__ wtO) {
  const int i = blockIdx.x * 256 + threadIdx.x;
  if (i < (int)WTI_ELEMS) {   // wtI[l][h][e] = bf16(Win[l][e][h])
    const int l = i / (384 * 128), r = i % (384 * 128), h = r >> 7, e = r & 127;
    wtI[i] = f2bf(Win[l * (128 * 384) + e * 384 + h]);
  }
  if (i < (int)WTO_ELEMS) {   // wtO[l][e][h] = bf16(Wout[l][h][e])
    const int l = i >> 14, r = i & 16383, e = r >> 7, h = r & 127;
    wtO[i] = f2bf(Wout[(l << 14) + h * 128 + e]);
  }
}

__device__ __forceinline__ bf16x8 load_xf(const float* xr) {
  const float4 a = *(const float4*)xr;
  const float4 c = *(const float4*)(xr + 4);
  bf16x8 f;
  f[0] = (short)f2bf(a.x); f[1] = (short)f2bf(a.y);
  f[2] = (short)f2bf(a.z); f[3] = (short)f2bf(a.w);
  f[4] = (short)f2bf(c.x); f[5] = (short)f2bf(c.y);
  f[6] = (short)f2bf(c.z); f[7] = (short)f2bf(c.w);
  return f;
}

template <bool WS>
__global__ __launch_bounds__(512, 2)
void ngatt_dual(const float* __restrict__ G, const int* __restrict__ nmask,
                const float* __restrict__ r3, const float* __restrict__ swg,
                const float* __restrict__ Win, const float* __restrict__ bin,
                const float* __restrict__ Wout, const float* __restrict__ bout,
                const float* __restrict__ lng, const float* __restrict__ lnb,
                const ushort_t* __restrict__ wtin, const ushort_t* __restrict__ wtout,
                float* __restrict__ xout) {
  extern __shared__ char smem[];
  ushort_t* bufA0 = (ushort_t*)smem;           // b0: q -> v -> VW^T
  ushort_t* bufB0 = bufA0 + BUF_US;            // b0: k -> P -> x' stash
  ushort_t* bufA1 = bufB0 + BUF_US;            // b1: q -> v -> VW^T
  ushort_t* bufB1 = bufA1 + BUF_US;            // b1: k -> P -> x' stash
  float* tab0 = (float*)(bufB1 + BUF_US);
  float* tab1 = tab0 + TAB_F;
  // per-b table layout (float offsets):
  //   pQ 0, pK 128, pV 256, sIV 384, fA 512..1023, fB 1024..1279,
  //   sSW 1280, sMK 1408, sRX 1536, sRY 1664, sRZ 1792

  const int bid = blockIdx.x, t = threadIdx.x;
  const int w = t >> 6, l = t & 63, lc = l & 15, lg = l >> 4;
  const int b0 = 2 * bid, b1 = b0 + 1;
  const size_t bb0 = (size_t)b0 * (128 * 128);
  const size_t bb1 = (size_t)b1 * (128 * 128);
  const int n_mine = 16 * w + lc;

  if (t < 256) {
    const int tb = t >> 7, tt = t & 127;
    float* T = tb ? tab1 : tab0;
    const size_t gi = (size_t)(b0 + tb) * 128 + tt;
    T[1280 + tt] = swg[gi];
    T[1408 + tt] = nmask[gi] ? 1.0f : 0.0f;
    T[1536 + tt] = r3[gi * 3 + 0];
    T[1664 + tt] = r3[gi * 3 + 1];
    T[1792 + tt] = r3[gi * 3 + 2];
  }
  __syncthreads();

  for (int layer = 0; layer < 2; ++layer) {
    const float* xsrc0 = layer ? (xout + bb0) : (G + bb0);
    const float* xsrc1 = layer ? (xout + bb1) : (G + bb1);
    const ushort_t* wtI = wtin + (size_t)layer * 384 * 128;
    const ushort_t* wtO = wtout + (size_t)layer * 128 * 128;
    const float* WinL  = Win  + (size_t)layer * 128 * 384;
    const float* WoutL = Wout + (size_t)layer * 128 * 128;
    const float* binL  = bin  + layer * 384;
    const float* boutL = bout + layer * 128;
    const float* lngL  = lng  + layer * 128;
    const float* lnbL  = lnb  + layer * 128;

    // ---- x B-fragments: layer 0 from global; layer 1 from bufB x' stash ----
    bf16x8 xf0[4], xf1[4];
    if (layer == 0) {
#pragma unroll
      for (int kk = 0; kk < 4; ++kk) {
        xf0[kk] = load_xf(xsrc0 + (size_t)n_mine * 128 + 8 * lg + 32 * kk);
        xf1[kk] = load_xf(xsrc1 + (size_t)n_mine * 128 + 8 * lg + 32 * kk);
      }
    } else {
#pragma unroll
      for (int kk = 0; kk < 4; ++kk) {
        xf0[kk] = *(const bf16x8*)(bufB0 + swz(n_mine, 8 * lg + 32 * kk));
        xf1[kk] = *(const bf16x8*)(bufB1 + swz(n_mine, 8 * lg + 32 * kk));
      }
    }

    // ---- q: tiles 0..7 -> bufA0/bufA1 (weights shared; NO prefetch) ----
    float ssq0 = 0.f, ssq1 = 0.f, ssk0 = 0.f, ssk1 = 0.f;
#pragma unroll 2
    for (int i = 0; i < 8; ++i) {
      bf16x8 aw[4];
#pragma unroll
      for (int kk = 0; kk < 4; ++kk)
        aw[kk] = wt_frag<WS>(wtI, WinL, 16 * i + lc, 8 * lg + 32 * kk, 384);
      f32x4 a0 = {0, 0, 0, 0}, a1 = {0, 0, 0, 0};
#pragma unroll
      for (int kk = 0; kk < 4; ++kk) {
        a0 = MFMA(aw[kk], xf0[kk], a0);
        a1 = MFMA(aw[kk], xf1[kk], a1);
      }
      const float4 bi = *(const float4*)&binL[16 * i + 4 * lg];
      {
        const float v0 = a0[0] + bi.x, v1 = a0[1] + bi.y, v2 = a0[2] + bi.z, v3 = a0[3] + bi.w;
        ssq0 += v0 * v0 + v1 * v1 + v2 * v2 + v3 * v3;
        *(ushort4*)(bufA0 + swz(n_mine, 16 * i + 4 * lg)) = pack4(v0, v1, v2, v3);
      }
      {
        const float v0 = a1[0] + bi.x, v1 = a1[1] + bi.y, v2 = a1[2] + bi.z, v3 = a1[3] + bi.w;
        ssq1 += v0 * v0 + v1 * v1 + v2 * v2 + v3 * v3;
        *(ushort4*)(bufA1 + swz(n_mine, 16 * i + 4 * lg)) = pack4(v0, v1, v2, v3);
      }
    }
    // ---- k: tiles 8..15 -> bufB0/bufB1 (own-band; xf already hoisted) ----
#pragma unroll 2
    for (int i = 0; i < 8; ++i) {
      bf16x8 aw[4];
#pragma unroll
      for (int kk = 0; kk < 4; ++kk)
        aw[kk] = wt_frag<WS>(wtI, WinL, 128 + 16 * i + lc, 8 * lg + 32 * kk, 384);
      f32x4 a0 = {0, 0, 0, 0}, a1 = {0, 0, 0, 0};
#pragma unroll
      for (int kk = 0; kk < 4; ++kk) {
        a0 = MFMA(aw[kk], xf0[kk], a0);
        a1 = MFMA(aw[kk], xf1[kk], a1);
      }
      const float4 bi = *(const float4*)&binL[128 + 16 * i + 4 * lg];
      {
        const float v0 = a0[0] + bi.x, v1 = a0[1] + bi.y, v2 = a0[2] + bi.z, v3 = a0[3] + bi.w;
        ssk0 += v0 * v0 + v1 * v1 + v2 * v2 + v3 * v3;
        *(ushort4*)(bufB0 + swz(n_mine, 16 * i + 4 * lg)) = pack4(v0, v1, v2, v3);
      }
      {
        const float v0 = a1[0] + bi.x, v1 = a1[1] + bi.y, v2 = a1[2] + bi.z, v3 = a1[3] + bi.w;
        ssk1 += v0 * v0 + v1 * v1 + v2 * v2 + v3 * v3;
        *(ushort4*)(bufB1 + swz(n_mine, 16 * i + 4 * lg)) = pack4(v0, v1, v2, v3);
      }
    }
    ssq0 += __shfl_xor(ssq0, 16); ssq0 += __shfl_xor(ssq0, 32);
    ssq1 += __shfl_xor(ssq1, 16); ssq1 += __shfl_xor(ssq1, 32);
    ssk0 += __shfl_xor(ssk0, 16); ssk0 += __shfl_xor(ssk0, 32);
    ssk1 += __shfl_xor(ssk1, 16); ssk1 += __shfl_xor(ssk1, 32);
    if (l < 16) {
      tab0[0 + n_mine] = ssq0; tab0[128 + n_mine] = ssk0;
      tab1[0 + n_mine] = ssq1; tab1[128 + n_mine] = ssk1;
    }
    __syncthreads();   // B1: q,k complete + norm partials

    if (t < 256) {
      const int tb = t >> 7, tt = t & 127;
      float* T = tb ? tab1 : tab0;
      T[0 + tt] = 1.0f / fmaxf(sqrtf(T[0 + tt]), 1e-12f);                 // 1/|q|
      T[512 + 4 * tt + 0] = (1.0f / fmaxf(sqrtf(T[128 + tt]), 1e-12f)) * F_SCALING;
      T[512 + 4 * tt + 1] = T[1280 + tt];   // sw
      T[512 + 4 * tt + 2] = 0.0f;
      T[512 + 4 * tt + 3] = T[1536 + tt];   // rx
      T[1024 + 2 * tt + 0] = T[1664 + tt];  // ry
      T[1024 + 2 * tt + 1] = T[1792 + tt];  // rz
    }
    // hoist q fragments for both b's (own rows)
    bf16x8 qf0[4], qf1[4];
#pragma unroll
    for (int kk = 0; kk < 4; ++kk) {
      qf0[kk] = *(const bf16x8*)(bufA0 + swz(n_mine, 8 * lg + 32 * kk));
      qf1[kk] = *(const bf16x8*)(bufA1 + swz(n_mine, 8 * lg + 32 * kk));
    }
    __syncthreads();   // B2: qf hoisted; factor tables ready; bufA free

    // ---- v: tiles 16..23 -> bufA0/bufA1 (weights shared; NO prefetch) ----
    float ssv0 = 0.f, ssv1 = 0.f;
#pragma unroll 2
    for (int i = 0; i < 8; ++i) {
      bf16x8 aw[4];
#pragma unroll
      for (int kk = 0; kk < 4; ++kk)
        aw[kk] = wt_frag<WS>(wtI, WinL, 256 + 16 * i + lc, 8 * lg + 32 * kk, 384);
      f32x4 a0 = {0, 0, 0, 0}, a1 = {0, 0, 0, 0};
#pragma unroll
      for (int kk = 0; kk < 4; ++kk) {
        a0 = MFMA(aw[kk], xf0[kk], a0);
        a1 = MFMA(aw[kk], xf1[kk], a1);
      }
      const float4 bi = *(const float4*)&binL[256 + 16 * i + 4 * lg];
      {
        const float v0 = a0[0] + bi.x, v1 = a0[1] + bi.y, v2 = a0[2] + bi.z, v3 = a0[3] + bi.w;
        ssv0 += v0 * v0 + v1 * v1 + v2 * v2 + v3 * v3;
        *(ushort4*)(bufA0 + swz(n_mine, 16 * i + 4 * lg)) = pack4(v0, v1, v2, v3);
      }
      {
        const float v0 = a1[0] + bi.x, v1 = a1[1] + bi.y, v2 = a1[2] + bi.z, v3 = a1[3] + bi.w;
        ssv1 += v0 * v0 + v1 * v1 + v2 * v2 + v3 * v3;
        *(ushort4*)(bufA1 + swz(n_mine, 16 * i + 4 * lg)) = pack4(v0, v1, v2, v3);
      }
    }
    ssv0 += __shfl_xor(ssv0, 16); ssv0 += __shfl_xor(ssv0, 32);
    ssv1 += __shfl_xor(ssv1, 16); ssv1 += __shfl_xor(ssv1, 32);
    if (l < 16) { tab0[256 + n_mine] = ssv0; tab1[256 + n_mine] = ssv1; }

    // ---- S + softmax, b0 then b1 (sequenced); EARLY bf16 pack of P ----
    ushort4 p0[8], p1[8];
    {
      const float iqn = tab0[0 + n_mine];
      const float swn = tab0[1280 + n_mine];
      const float rxn = tab0[1536 + n_mine], ryn = tab0[1664 + n_mine], rzn = tab0[1792 + n_mine];
      float sum = 0.0f;
      f32x4 sacc[8];
#pragma unroll 2
      for (int mt = 0; mt < 8; ++mt) {
        bf16x8 kf[4];
#pragma unroll
        for (int kk = 0; kk < 4; ++kk)
          kf[kk] = *(const bf16x8*)(bufB0 + swz(16 * mt + lc, 8 * lg + 32 * kk));
        __builtin_amdgcn_s_setprio(1);
        f32x4 a = {0, 0, 0, 0};
#pragma unroll
        for (int kk = 0; kk < 4; ++kk) a = MFMA(kf[kk], qf0[kk], a);
        __builtin_amdgcn_s_setprio(0);
#pragma unroll
        for (int r2 = 0; r2 < 4; ++r2) {
          const int m = 16 * mt + 4 * lg + r2;
          const float4 a4 = *(const float4*)&tab0[512 + 4 * m];
          const float2 b2 = *(const float2*)&tab0[1024 + 2 * m];
          const float sws = swn * a4.y;
          const float e = __expf((a[r2] * iqn * a4.x + F_SHIFT) * sws - F_SHIFT);
          sum += e;
          a[r2] = e * sws * (rxn * a4.w + ryn * b2.x + rzn * b2.y);
        }
        sacc[mt] = a;
      }
      sum += __shfl_xor(sum, 16); sum += __shfl_xor(sum, 32);
      const float fac = tab0[1408 + n_mine] / sum;
#pragma unroll
      for (int mt = 0; mt < 8; ++mt)
        p0[mt] = pack4(sacc[mt][0] * fac, sacc[mt][1] * fac, sacc[mt][2] * fac, sacc[mt][3] * fac);
    }
    {
      const float iqn = tab1[0 + n_mine];
      const float swn = tab1[1280 + n_mine];
      const float rxn = tab1[1536 + n_mine], ryn = tab1[1664 + n_mine], rzn = tab1[1792 + n_mine];
      float sum = 0.0f;
      f32x4 sacc[8];
#pragma unroll 2
      for (int mt = 0; mt < 8; ++mt) {
        bf16x8 kf[4];
#pragma unroll
        for (int kk = 0; kk < 4; ++kk)
          kf[kk] = *(const bf16x8*)(bufB1 + swz(16 * mt + lc, 8 * lg + 32 * kk));
        __builtin_amdgcn_s_setprio(1);
        f32x4 a = {0, 0, 0, 0};
#pragma unroll
        for (int kk = 0; kk < 4; ++kk) a = MFMA(kf[kk], qf1[kk], a);
        __builtin_amdgcn_s_setprio(0);
#pragma unroll
        for (int r2 = 0; r2 < 4; ++r2) {
          const int m = 16 * mt + 4 * lg + r2;
          const float4 a4 = *(const float4*)&tab1[512 + 4 * m];
          const float2 b2 = *(const float2*)&tab1[1024 + 2 * m];
          const float sws = swn * a4.y;
          const float e = __expf((a[r2] * iqn * a4.x + F_SHIFT) * sws - F_SHIFT);
          sum += e;
          a[r2] = e * sws * (rxn * a4.w + ryn * b2.x + rzn * b2.y);
        }
        sacc[mt] = a;
      }
      sum += __shfl_xor(sum, 16); sum += __shfl_xor(sum, 32);
      const float fac = tab1[1408 + n_mine] / sum;
#pragma unroll
      for (int mt = 0; mt < 8; ++mt)
        p1[mt] = pack4(sacc[mt][0] * fac, sacc[mt][1] * fac, sacc[mt][2] * fac, sacc[mt][3] * fac);
    }
    __syncthreads();   // B3: v writes + pV done; all S reads of bufB done

    if (t < 256) {
      const int tb = t >> 7, tt = t & 127;
      float* T = tb ? tab1 : tab0;
      T[384 + tt] = 1.0f / fmaxf(sqrtf(T[256 + tt]), 1e-12f);   // 1/|v|
    }
    // store pre-packed P -> bufB (own rows)
#pragma unroll
    for (int mt = 0; mt < 8; ++mt) {
      *(ushort4*)(bufB0 + swz(n_mine, 16 * mt + 4 * lg)) = p0[mt];
      *(ushort4*)(bufB1 + swz(n_mine, 16 * mt + 4 * lg)) = p1[mt];
    }
    // hoist v fragments (own rows)
    bf16x8 vf0[4], vf1[4];
#pragma unroll
    for (int kk = 0; kk < 4; ++kk) {
      vf0[kk] = *(const bf16x8*)(bufA0 + swz(n_mine, 8 * lg + 32 * kk));
      vf1[kk] = *(const bf16x8*)(bufA1 + swz(n_mine, 8 * lg + 32 * kk));
    }
    __syncthreads();   // B4: P stored, vf hoisted, sIV ready; bufA free

    // ---- VW^T = (v @ W_out)^T * iv -> bufA (weights shared; NO prefetch) ----
    {
      const float4 iv0 = *(const float4*)&tab0[384 + 16 * w + 4 * lg];
      const float4 iv1 = *(const float4*)&tab1[384 + 16 * w + 4 * lg];
#pragma unroll 2
      for (int i = 0; i < 8; ++i) {
        bf16x8 bw[4];
#pragma unroll
        for (int kk = 0; kk < 4; ++kk)
          bw[kk] = wt_frag<WS>(wtO, WoutL, 16 * i + lc, 8 * lg + 32 * kk, 128);
        f32x4 a0 = {0, 0, 0, 0}, a1 = {0, 0, 0, 0};
#pragma unroll
        for (int kk = 0; kk < 4; ++kk) {
          a0 = MFMA(vf0[kk], bw[kk], a0);
          a1 = MFMA(vf1[kk], bw[kk], a1);
        }
        *(ushort4*)(bufA0 + swz(16 * i + lc, 16 * w + 4 * lg)) =
            pack4(a0[0] * iv0.x, a0[1] * iv0.y, a0[2] * iv0.z, a0[3] * iv0.w);
        *(ushort4*)(bufA1 + swz(16 * i + lc, 16 * w + 4 * lg)) =
            pack4(a1[0] * iv1.x, a1[1] * iv1.y, a1[2] * iv1.z, a1[3] * iv1.w);
      }
    }
    __syncthreads();   // B5: VW^T complete

    // ---- PV + LN epilogue, b0 then b1 (sequenced).
    //      pf hoisted per-which; residual loads hoisted before PV MFMAs.
    //      Layer 0: also stash f2bf(x') into bufB own-band rows. ----
    float bo8[8], g8[8], be8[8];
#pragma unroll
    for (int ct = 0; ct < 8; ++ct) {
      const int e = 16 * ct + lc;
      bo8[ct] = boutL[e]; g8[ct] = lngL[e]; be8[ct] = lnbL[e];
    }
#pragma unroll 1
    for (int which = 0; which < 2; ++which) {
      const ushort_t* bufA = which ? bufA1 : bufA0;
      ushort_t* bufB = which ? bufB1 : bufB0;
      const float* xsrc = which ? xsrc1 : xsrc0;
      float* xo = xout + (which ? bb1 : bb0);

      // residual hoist: 32 floats, issued early (independent HBM loads)
      float xr8[4][8];
#pragma unroll
      for (int r2 = 0; r2 < 4; ++r2) {
        const float* xr = xsrc + (size_t)(16 * w + 4 * lg + r2) * 128;
#pragma unroll
        for (int ct = 0; ct < 8; ++ct) xr8[r2][ct] = xr[16 * ct + lc];
      }

      // pf hoist (own rows; bufB untouched since P store)
      bf16x8 pf[4];
#pragma unroll
      for (int kk = 0; kk < 4; ++kk)
        pf[kk] = *(const bf16x8*)(bufB + swz(n_mine, 8 * lg + 32 * kk));

      f32x4 oacc[8];
#pragma unroll 2
      for (int i = 0; i < 8; ++i) {
        bf16x8 bf[4];
#pragma unroll
        for (int kk = 0; kk < 4; ++kk)
          bf[kk] = *(const bf16x8*)(bufA + swz(16 * i + lc, 8 * lg + 32 * kk));
        __builtin_amdgcn_s_setprio(1);
        f32x4 a = {0, 0, 0, 0};
#pragma unroll
        for (int kk = 0; kk < 4; ++kk) a = MFMA(pf[kk], bf[kk], a);
        __builtin_amdgcn_s_setprio(0);
        oacc[i] = a;
      }
#pragma unroll
      for (int r2 = 0; r2 < 4; ++r2) {
        const int n = 16 * w + 4 * lg + r2;
        float vals[8];
        float s1 = 0.0f, s2 = 0.0f;
#pragma unroll
        for (int ct = 0; ct < 8; ++ct) {
          const float v = oacc[ct][r2] + bo8[ct] + xr8[r2][ct];
          vals[ct] = v; s1 += v; s2 += v * v;
        }
        s1 += __shfl_xor(s1, 1); s1 += __shfl_xor(s1, 2);
        s1 += __shfl_xor(s1, 4); s1 += __shfl_xor(s1, 8);
        s2 += __shfl_xor(s2, 1); s2 += __shfl_xor(s2, 2);
        s2 += __shfl_xor(s2, 4); s2 += __shfl_xor(s2, 8);
        const float mu = s1 * (1.0f / 128.0f);
        const float rs = rsqrtf(s2 * (1.0f / 128.0f) - mu * mu + F_LNEPS);
        float* orow = xo + (size_t)n * 128;
        if (layer == 0) {
#pragma unroll
          for (int ct = 0; ct < 8; ++ct) {
            const float y = (vals[ct] - mu) * rs * g8[ct] + be8[ct];
            orow[16 * ct + lc] = y;
            bufB[swz(n, 16 * ct + lc)] = f2bf(y);   // own-band x' stash
          }
        } else {
#pragma unroll
          for (int ct = 0; ct < 8; ++ct)
            orow[16 * ct + lc] = (vals[ct] - mu) * rs * g8[ct] + be8[ct];
        }
      }
    }
    __syncthreads();   // B6: layer boundary (buffers reused; xout -> next xsrc)
  }
}

extern "C" void kernel_launch(void* const* d_in, const int* in_sizes, int n_in,
                              void* d_out, int out_size, void* d_ws, size_t ws_size,
                              hipStream_t stream) {
  const float* G    = (const float*)d_in[0];
  const int*   msk  = (const int*)d_in[1];
  const float* r3   = (const float*)d_in[2];
  const float* swg  = (const float*)d_in[3];
  const float* Win  = (const float*)d_in[4];
  const float* bin  = (const float*)d_in[5];
  const float* Wout = (const float*)d_in[6];
  const float* bout = (const float*)d_in[7];
  const float* lng  = (const float*)d_in[8];
  const float* lnb  = (const float*)d_in[9];
  float* xout = (float*)d_out;

  const int B = in_sizes[0] / (128 * 128);
  const int nblk = B / 2;
  const bool ws_ok = ws_size >= (WTI_ELEMS + WTO_ELEMS) * sizeof(ushort_t);
  ushort_t* wtI = (ushort_t*)d_ws;
  ushort_t* wtO = wtI + WTI_ELEMS;

  if (ws_ok) {
    prep_weights<<<dim3(384), dim3(256), 0, stream>>>(Win, Wout, wtI, wtO);
    hipFuncSetAttribute(reinterpret_cast<const void*>(ngatt_dual<true>),
                        hipFuncAttributeMaxDynamicSharedMemorySize, LDS_BYTES);
    ngatt_dual<true><<<dim3(nblk), dim3(512), LDS_BYTES, stream>>>(
        G, msk, r3, swg, Win, bin, Wout, bout, lng, lnb, wtI, wtO, xout);
  } else {
    hipFuncSetAttribute(reinterpret_cast<const void*>(ngatt_dual<false>),
                        hipFuncAttributeMaxDynamicSharedMemorySize, LDS_BYTES);
    ngatt_dual<false><<<dim3(nblk), dim3(512), LDS_BYTES, stream>>>(
        G, msk, r3, swg, Win, bin, Wout, bout, lng, lnb, nullptr, nullptr, xout);
  }
}

// Round 18
// 1651.330 us; speedup vs baseline: 1.1220x; 1.1220x over previous
//
#include <hip/hip_runtime.h>
#include <hip/hip_bf16.h>
#include <math.h>

// NeighborGatedAttention, bf16-MFMA, DUAL-b (R16 minus s_setprio).
// L=2, B=8192, NNEI=128, EMB=HID=128. One block (512 thr = 8 waves), TWO b's.
// R16 (1660us, best): R13 + layer-0 x' bf16 stash in bufB (layer-1 xf from
// LDS, -21% FETCH). This round: A/B remove s_setprio (entered R13 bundled;
// T5 evidence says it hurts near-lockstep schedules, m190 GEMM -14TF).
// R17 lesson: the 6.3e7 bank conflicts are NOT the fragment reads (swizzle
// left the count bit-identical and regressed via +addr VALU / VGPR 128).
// LDS 154.6KB, 1 block/CU, 2 waves/SIMD. No prefetch (R10-12: spills).

typedef __attribute__((ext_vector_type(8))) short bf16x8; // 8 bf16 = 4 VGPR
typedef __attribute__((ext_vector_type(4))) float f32x4;
typedef unsigned short ushort_t;

constexpr float F_SHIFT   = 20.0f;
constexpr float F_SCALING = 0.08838834764831845f; // 128^-0.5
constexpr float F_LNEPS   = 1e-5f;

constexpr int ROWP = 136;                 // ushort row pitch (272B)
constexpr int BUF_US = 128 * ROWP;        // 17408 ushorts per buffer
constexpr size_t WTI_ELEMS = 2 * 384 * 128;
constexpr size_t WTO_ELEMS = 2 * 128 * 128;
constexpr int TAB_F = 1920;               // per-b table floats
constexpr int LDS_BYTES = 4 * BUF_US * 2 + 2 * TAB_F * 4; // 154624

#define MFMA(a, b, c) __builtin_amdgcn_mfma_f32_16x16x32_bf16(a, b, c, 0, 0, 0)

__device__ __forceinline__ ushort_t f2bf(float f) {
  __hip_bfloat16 h = __float2bfloat16(f);
  return *reinterpret_cast<ushort_t*>(&h);
}
__device__ __forceinline__ ushort4 pack4(float a, float b, float c, float d) {
  return make_ushort4(f2bf(a), f2bf(b), f2bf(c), f2bf(d));
}

// A/B fragment from pre-transposed bf16 weights (WS) or fp32 gather fallback.
template <bool WS>
__device__ __forceinline__ bf16x8 wt_frag(const ushort_t* __restrict__ wt,
                                          const float* __restrict__ W,
                                          int r, int c, int ldW) {
  if constexpr (WS) {
    return *(const bf16x8*)(wt + r * 128 + c);
  } else {
    bf16x8 f;
#pragma unroll
    for (int j = 0; j < 8; ++j) f[j] = (short)f2bf(W[(size_t)(c + j) * ldW + r]);
    return f;
  }
}

__global__ void prep_weights(const float* __restrict__ Win, const float* __restrict__ Wout,
                             ushort_t* __restrict__ wtI, ushort_t* __restrict__ wtO) {
  const int i = blockIdx.x * 256 + threadIdx.x;
  if (i < (int)WTI_ELEMS) {   // wtI[l][h][e] = bf16(Win[l][e][h])
    const int l = i / (384 * 128), r = i % (384 * 128), h = r >> 7, e = r & 127;
    wtI[i] = f2bf(Win[l * (128 * 384) + e * 384 + h]);
  }
  if (i < (int)WTO_ELEMS) {   // wtO[l][e][h] = bf16(Wout[l][h][e])
    const int l = i >> 14, r = i & 16383, e = r >> 7, h = r & 127;
    wtO[i] = f2bf(Wout[(l << 14) + h * 128 + e]);
  }
}

__device__ __forceinline__ bf16x8 load_xf(const float* xr) {
  const float4 a = *(const float4*)xr;
  const float4 c = *(const float4*)(xr + 4);
  bf16x8 f;
  f[0] = (short)f2bf(a.x); f[1] = (short)f2bf(a.y);
  f[2] = (short)f2bf(a.z); f[3] = (short)f2bf(a.w);
  f[4] = (short)f2bf(c.x); f[5] = (short)f2bf(c.y);
  f[6] = (short)f2bf(c.z); f[7] = (short)f2bf(c.w);
  return f;
}

template <bool WS>
__global__ __launch_bounds__(512, 2)
void ngatt_dual(const float* __restrict__ G, const int* __restrict__ nmask,
                const float* __restrict__ r3, const float* __restrict__ swg,
                const float* __restrict__ Win, const float* __restrict__ bin,
                const float* __restrict__ Wout, const float* __restrict__ bout,
                const float* __restrict__ lng, const float* __restrict__ lnb,
                const ushort_t* __restrict__ wtin, const ushort_t* __restrict__ wtout,
                float* __restrict__ xout) {
  extern __shared__ char smem[];
  ushort_t* bufA0 = (ushort_t*)smem;           // b0: q -> v -> VW^T
  ushort_t* bufB0 = bufA0 + BUF_US;            // b0: k -> P -> x' stash
  ushort_t* bufA1 = bufB0 + BUF_US;            // b1: q -> v -> VW^T
  ushort_t* bufB1 = bufA1 + BUF_US;            // b1: k -> P -> x' stash
  float* tab0 = (float*)(bufB1 + BUF_US);
  float* tab1 = tab0 + TAB_F;
  // per-b table layout (float offsets):
  //   pQ 0, pK 128, pV 256, sIV 384, fA 512..1023, fB 1024..1279,
  //   sSW 1280, sMK 1408, sRX 1536, sRY 1664, sRZ 1792

  const int bid = blockIdx.x, t = threadIdx.x;
  const int w = t >> 6, l = t & 63, lc = l & 15, lg = l >> 4;
  const int b0 = 2 * bid, b1 = b0 + 1;
  const size_t bb0 = (size_t)b0 * (128 * 128);
  const size_t bb1 = (size_t)b1 * (128 * 128);
  const int n_mine = 16 * w + lc;

  if (t < 256) {
    const int tb = t >> 7, tt = t & 127;
    float* T = tb ? tab1 : tab0;
    const size_t gi = (size_t)(b0 + tb) * 128 + tt;
    T[1280 + tt] = swg[gi];
    T[1408 + tt] = nmask[gi] ? 1.0f : 0.0f;
    T[1536 + tt] = r3[gi * 3 + 0];
    T[1664 + tt] = r3[gi * 3 + 1];
    T[1792 + tt] = r3[gi * 3 + 2];
  }
  __syncthreads();

  for (int layer = 0; layer < 2; ++layer) {
    const float* xsrc0 = layer ? (xout + bb0) : (G + bb0);
    const float* xsrc1 = layer ? (xout + bb1) : (G + bb1);
    const ushort_t* wtI = wtin + (size_t)layer * 384 * 128;
    const ushort_t* wtO = wtout + (size_t)layer * 128 * 128;
    const float* WinL  = Win  + (size_t)layer * 128 * 384;
    const float* WoutL = Wout + (size_t)layer * 128 * 128;
    const float* binL  = bin  + layer * 384;
    const float* boutL = bout + layer * 128;
    const float* lngL  = lng  + layer * 128;
    const float* lnbL  = lnb  + layer * 128;

    // ---- x B-fragments: layer 0 from global; layer 1 from bufB x' stash ----
    bf16x8 xf0[4], xf1[4];
    if (layer == 0) {
#pragma unroll
      for (int kk = 0; kk < 4; ++kk) {
        xf0[kk] = load_xf(xsrc0 + (size_t)n_mine * 128 + 8 * lg + 32 * kk);
        xf1[kk] = load_xf(xsrc1 + (size_t)n_mine * 128 + 8 * lg + 32 * kk);
      }
    } else {
#pragma unroll
      for (int kk = 0; kk < 4; ++kk) {
        xf0[kk] = *(const bf16x8*)(bufB0 + n_mine * ROWP + 8 * lg + 32 * kk);
        xf1[kk] = *(const bf16x8*)(bufB1 + n_mine * ROWP + 8 * lg + 32 * kk);
      }
    }

    // ---- q: tiles 0..7 -> bufA0/bufA1 (weights shared; NO prefetch) ----
    float ssq0 = 0.f, ssq1 = 0.f, ssk0 = 0.f, ssk1 = 0.f;
#pragma unroll 2
    for (int i = 0; i < 8; ++i) {
      bf16x8 aw[4];
#pragma unroll
      for (int kk = 0; kk < 4; ++kk)
        aw[kk] = wt_frag<WS>(wtI, WinL, 16 * i + lc, 8 * lg + 32 * kk, 384);
      f32x4 a0 = {0, 0, 0, 0}, a1 = {0, 0, 0, 0};
#pragma unroll
      for (int kk = 0; kk < 4; ++kk) {
        a0 = MFMA(aw[kk], xf0[kk], a0);
        a1 = MFMA(aw[kk], xf1[kk], a1);
      }
      const float4 bi = *(const float4*)&binL[16 * i + 4 * lg];
      {
        const float v0 = a0[0] + bi.x, v1 = a0[1] + bi.y, v2 = a0[2] + bi.z, v3 = a0[3] + bi.w;
        ssq0 += v0 * v0 + v1 * v1 + v2 * v2 + v3 * v3;
        *(ushort4*)(bufA0 + n_mine * ROWP + 16 * i + 4 * lg) = pack4(v0, v1, v2, v3);
      }
      {
        const float v0 = a1[0] + bi.x, v1 = a1[1] + bi.y, v2 = a1[2] + bi.z, v3 = a1[3] + bi.w;
        ssq1 += v0 * v0 + v1 * v1 + v2 * v2 + v3 * v3;
        *(ushort4*)(bufA1 + n_mine * ROWP + 16 * i + 4 * lg) = pack4(v0, v1, v2, v3);
      }
    }
    // ---- k: tiles 8..15 -> bufB0/bufB1 (own-band; xf already hoisted) ----
#pragma unroll 2
    for (int i = 0; i < 8; ++i) {
      bf16x8 aw[4];
#pragma unroll
      for (int kk = 0; kk < 4; ++kk)
        aw[kk] = wt_frag<WS>(wtI, WinL, 128 + 16 * i + lc, 8 * lg + 32 * kk, 384);
      f32x4 a0 = {0, 0, 0, 0}, a1 = {0, 0, 0, 0};
#pragma unroll
      for (int kk = 0; kk < 4; ++kk) {
        a0 = MFMA(aw[kk], xf0[kk], a0);
        a1 = MFMA(aw[kk], xf1[kk], a1);
      }
      const float4 bi = *(const float4*)&binL[128 + 16 * i + 4 * lg];
      {
        const float v0 = a0[0] + bi.x, v1 = a0[1] + bi.y, v2 = a0[2] + bi.z, v3 = a0[3] + bi.w;
        ssk0 += v0 * v0 + v1 * v1 + v2 * v2 + v3 * v3;
        *(ushort4*)(bufB0 + n_mine * ROWP + 16 * i + 4 * lg) = pack4(v0, v1, v2, v3);
      }
      {
        const float v0 = a1[0] + bi.x, v1 = a1[1] + bi.y, v2 = a1[2] + bi.z, v3 = a1[3] + bi.w;
        ssk1 += v0 * v0 + v1 * v1 + v2 * v2 + v3 * v3;
        *(ushort4*)(bufB1 + n_mine * ROWP + 16 * i + 4 * lg) = pack4(v0, v1, v2, v3);
      }
    }
    ssq0 += __shfl_xor(ssq0, 16); ssq0 += __shfl_xor(ssq0, 32);
    ssq1 += __shfl_xor(ssq1, 16); ssq1 += __shfl_xor(ssq1, 32);
    ssk0 += __shfl_xor(ssk0, 16); ssk0 += __shfl_xor(ssk0, 32);
    ssk1 += __shfl_xor(ssk1, 16); ssk1 += __shfl_xor(ssk1, 32);
    if (l < 16) {
      tab0[0 + n_mine] = ssq0; tab0[128 + n_mine] = ssk0;
      tab1[0 + n_mine] = ssq1; tab1[128 + n_mine] = ssk1;
    }
    __syncthreads();   // B1: q,k complete + norm partials

    if (t < 256) {
      const int tb = t >> 7, tt = t & 127;
      float* T = tb ? tab1 : tab0;
      T[0 + tt] = 1.0f / fmaxf(sqrtf(T[0 + tt]), 1e-12f);                 // 1/|q|
      T[512 + 4 * tt + 0] = (1.0f / fmaxf(sqrtf(T[128 + tt]), 1e-12f)) * F_SCALING;
      T[512 + 4 * tt + 1] = T[1280 + tt];   // sw
      T[512 + 4 * tt + 2] = 0.0f;
      T[512 + 4 * tt + 3] = T[1536 + tt];   // rx
      T[1024 + 2 * tt + 0] = T[1664 + tt];  // ry
      T[1024 + 2 * tt + 1] = T[1792 + tt];  // rz
    }
    // hoist q fragments for both b's (own rows)
    bf16x8 qf0[4], qf1[4];
#pragma unroll
    for (int kk = 0; kk < 4; ++kk) {
      qf0[kk] = *(const bf16x8*)(bufA0 + n_mine * ROWP + 8 * lg + 32 * kk);
      qf1[kk] = *(const bf16x8*)(bufA1 + n_mine * ROWP + 8 * lg + 32 * kk);
    }
    __syncthreads();   // B2: qf hoisted; factor tables ready; bufA free

    // ---- v: tiles 16..23 -> bufA0/bufA1 (weights shared; NO prefetch) ----
    float ssv0 = 0.f, ssv1 = 0.f;
#pragma unroll 2
    for (int i = 0; i < 8; ++i) {
      bf16x8 aw[4];
#pragma unroll
      for (int kk = 0; kk < 4; ++kk)
        aw[kk] = wt_frag<WS>(wtI, WinL, 256 + 16 * i + lc, 8 * lg + 32 * kk, 384);
      f32x4 a0 = {0, 0, 0, 0}, a1 = {0, 0, 0, 0};
#pragma unroll
      for (int kk = 0; kk < 4; ++kk) {
        a0 = MFMA(aw[kk], xf0[kk], a0);
        a1 = MFMA(aw[kk], xf1[kk], a1);
      }
      const float4 bi = *(const float4*)&binL[256 + 16 * i + 4 * lg];
      {
        const float v0 = a0[0] + bi.x, v1 = a0[1] + bi.y, v2 = a0[2] + bi.z, v3 = a0[3] + bi.w;
        ssv0 += v0 * v0 + v1 * v1 + v2 * v2 + v3 * v3;
        *(ushort4*)(bufA0 + n_mine * ROWP + 16 * i + 4 * lg) = pack4(v0, v1, v2, v3);
      }
      {
        const float v0 = a1[0] + bi.x, v1 = a1[1] + bi.y, v2 = a1[2] + bi.z, v3 = a1[3] + bi.w;
        ssv1 += v0 * v0 + v1 * v1 + v2 * v2 + v3 * v3;
        *(ushort4*)(bufA1 + n_mine * ROWP + 16 * i + 4 * lg) = pack4(v0, v1, v2, v3);
      }
    }
    ssv0 += __shfl_xor(ssv0, 16); ssv0 += __shfl_xor(ssv0, 32);
    ssv1 += __shfl_xor(ssv1, 16); ssv1 += __shfl_xor(ssv1, 32);
    if (l < 16) { tab0[256 + n_mine] = ssv0; tab1[256 + n_mine] = ssv1; }

    // ---- S + softmax, b0 then b1 (sequenced); EARLY bf16 pack of P ----
    ushort4 p0[8], p1[8];
    {
      const float iqn = tab0[0 + n_mine];
      const float swn = tab0[1280 + n_mine];
      const float rxn = tab0[1536 + n_mine], ryn = tab0[1664 + n_mine], rzn = tab0[1792 + n_mine];
      float sum = 0.0f;
      f32x4 sacc[8];
#pragma unroll 2
      for (int mt = 0; mt < 8; ++mt) {
        bf16x8 kf[4];
#pragma unroll
        for (int kk = 0; kk < 4; ++kk)
          kf[kk] = *(const bf16x8*)(bufB0 + (16 * mt + lc) * ROWP + 8 * lg + 32 * kk);
        f32x4 a = {0, 0, 0, 0};
#pragma unroll
        for (int kk = 0; kk < 4; ++kk) a = MFMA(kf[kk], qf0[kk], a);
#pragma unroll
        for (int r2 = 0; r2 < 4; ++r2) {
          const int m = 16 * mt + 4 * lg + r2;
          const float4 a4 = *(const float4*)&tab0[512 + 4 * m];
          const float2 b2 = *(const float2*)&tab0[1024 + 2 * m];
          const float sws = swn * a4.y;
          const float e = __expf((a[r2] * iqn * a4.x + F_SHIFT) * sws - F_SHIFT);
          sum += e;
          a[r2] = e * sws * (rxn * a4.w + ryn * b2.x + rzn * b2.y);
        }
        sacc[mt] = a;
      }
      sum += __shfl_xor(sum, 16); sum += __shfl_xor(sum, 32);
      const float fac = tab0[1408 + n_mine] / sum;
#pragma unroll
      for (int mt = 0; mt < 8; ++mt)
        p0[mt] = pack4(sacc[mt][0] * fac, sacc[mt][1] * fac, sacc[mt][2] * fac, sacc[mt][3] * fac);
    }
    {
      const float iqn = tab1[0 + n_mine];
      const float swn = tab1[1280 + n_mine];
      const float rxn = tab1[1536 + n_mine], ryn = tab1[1664 + n_mine], rzn = tab1[1792 + n_mine];
      float sum = 0.0f;
      f32x4 sacc[8];
#pragma unroll 2
      for (int mt = 0; mt < 8; ++mt) {
        bf16x8 kf[4];
#pragma unroll
        for (int kk = 0; kk < 4; ++kk)
          kf[kk] = *(const bf16x8*)(bufB1 + (16 * mt + lc) * ROWP + 8 * lg + 32 * kk);
        f32x4 a = {0, 0, 0, 0};
#pragma unroll
        for (int kk = 0; kk < 4; ++kk) a = MFMA(kf[kk], qf1[kk], a);
#pragma unroll
        for (int r2 = 0; r2 < 4; ++r2) {
          const int m = 16 * mt + 4 * lg + r2;
          const float4 a4 = *(const float4*)&tab1[512 + 4 * m];
          const float2 b2 = *(const float2*)&tab1[1024 + 2 * m];
          const float sws = swn * a4.y;
          const float e = __expf((a[r2] * iqn * a4.x + F_SHIFT) * sws - F_SHIFT);
          sum += e;
          a[r2] = e * sws * (rxn * a4.w + ryn * b2.x + rzn * b2.y);
        }
        sacc[mt] = a;
      }
      sum += __shfl_xor(sum, 16); sum += __shfl_xor(sum, 32);
      const float fac = tab1[1408 + n_mine] / sum;
#pragma unroll
      for (int mt = 0; mt < 8; ++mt)
        p1[mt] = pack4(sacc[mt][0] * fac, sacc[mt][1] * fac, sacc[mt][2] * fac, sacc[mt][3] * fac);
    }
    __syncthreads();   // B3: v writes + pV done; all S reads of bufB done

    if (t < 256) {
      const int tb = t >> 7, tt = t & 127;
      float* T = tb ? tab1 : tab0;
      T[384 + tt] = 1.0f / fmaxf(sqrtf(T[256 + tt]), 1e-12f);   // 1/|v|
    }
    // store pre-packed P -> bufB (own rows)
#pragma unroll
    for (int mt = 0; mt < 8; ++mt) {
      *(ushort4*)(bufB0 + n_mine * ROWP + 16 * mt + 4 * lg) = p0[mt];
      *(ushort4*)(bufB1 + n_mine * ROWP + 16 * mt + 4 * lg) = p1[mt];
    }
    // hoist v fragments (own rows)
    bf16x8 vf0[4], vf1[4];
#pragma unroll
    for (int kk = 0; kk < 4; ++kk) {
      vf0[kk] = *(const bf16x8*)(bufA0 + n_mine * ROWP + 8 * lg + 32 * kk);
      vf1[kk] = *(const bf16x8*)(bufA1 + n_mine * ROWP + 8 * lg + 32 * kk);
    }
    __syncthreads();   // B4: P stored, vf hoisted, sIV ready; bufA free

    // ---- VW^T = (v @ W_out)^T * iv -> bufA (weights shared; NO prefetch) ----
    {
      const float4 iv0 = *(const float4*)&tab0[384 + 16 * w + 4 * lg];
      const float4 iv1 = *(const float4*)&tab1[384 + 16 * w + 4 * lg];
#pragma unroll 2
      for (int i = 0; i < 8; ++i) {
        bf16x8 bw[4];
#pragma unroll
        for (int kk = 0; kk < 4; ++kk)
          bw[kk] = wt_frag<WS>(wtO, WoutL, 16 * i + lc, 8 * lg + 32 * kk, 128);
        f32x4 a0 = {0, 0, 0, 0}, a1 = {0, 0, 0, 0};
#pragma unroll
        for (int kk = 0; kk < 4; ++kk) {
          a0 = MFMA(vf0[kk], bw[kk], a0);
          a1 = MFMA(vf1[kk], bw[kk], a1);
        }
        *(ushort4*)(bufA0 + (16 * i + lc) * ROWP + 16 * w + 4 * lg) =
            pack4(a0[0] * iv0.x, a0[1] * iv0.y, a0[2] * iv0.z, a0[3] * iv0.w);
        *(ushort4*)(bufA1 + (16 * i + lc) * ROWP + 16 * w + 4 * lg) =
            pack4(a1[0] * iv1.x, a1[1] * iv1.y, a1[2] * iv1.z, a1[3] * iv1.w);
      }
    }
    __syncthreads();   // B5: VW^T complete

    // ---- PV + LN epilogue, b0 then b1 (sequenced).
    //      pf hoisted per-which; residual loads hoisted before PV MFMAs.
    //      Layer 0: also stash f2bf(x') into bufB own-band rows. ----
    float bo8[8], g8[8], be8[8];
#pragma unroll
    for (int ct = 0; ct < 8; ++ct) {
      const int e = 16 * ct + lc;
      bo8[ct] = boutL[e]; g8[ct] = lngL[e]; be8[ct] = lnbL[e];
    }
#pragma unroll 1
    for (int which = 0; which < 2; ++which) {
      const ushort_t* bufA = which ? bufA1 : bufA0;
      ushort_t* bufB = which ? bufB1 : bufB0;
      const float* xsrc = which ? xsrc1 : xsrc0;
      float* xo = xout + (which ? bb1 : bb0);

      // residual hoist: 32 floats, issued early (independent HBM loads)
      float xr8[4][8];
#pragma unroll
      for (int r2 = 0; r2 < 4; ++r2) {
        const float* xr = xsrc + (size_t)(16 * w + 4 * lg + r2) * 128;
#pragma unroll
        for (int ct = 0; ct < 8; ++ct) xr8[r2][ct] = xr[16 * ct + lc];
      }

      // pf hoist (own rows; bufB untouched since P store)
      bf16x8 pf[4];
#pragma unroll
      for (int kk = 0; kk < 4; ++kk)
        pf[kk] = *(const bf16x8*)(bufB + n_mine * ROWP + 8 * lg + 32 * kk);

      f32x4 oacc[8];
#pragma unroll 2
      for (int i = 0; i < 8; ++i) {
        bf16x8 bf[4];
#pragma unroll
        for (int kk = 0; kk < 4; ++kk)
          bf[kk] = *(const bf16x8*)(bufA + (16 * i + lc) * ROWP + 8 * lg + 32 * kk);
        f32x4 a = {0, 0, 0, 0};
#pragma unroll
        for (int kk = 0; kk < 4; ++kk) a = MFMA(pf[kk], bf[kk], a);
        oacc[i] = a;
      }
#pragma unroll
      for (int r2 = 0; r2 < 4; ++r2) {
        const int n = 16 * w + 4 * lg + r2;
        float vals[8];
        float s1 = 0.0f, s2 = 0.0f;
#pragma unroll
        for (int ct = 0; ct < 8; ++ct) {
          const float v = oacc[ct][r2] + bo8[ct] + xr8[r2][ct];
          vals[ct] = v; s1 += v; s2 += v * v;
        }
        s1 += __shfl_xor(s1, 1); s1 += __shfl_xor(s1, 2);
        s1 += __shfl_xor(s1, 4); s1 += __shfl_xor(s1, 8);
        s2 += __shfl_xor(s2, 1); s2 += __shfl_xor(s2, 2);
        s2 += __shfl_xor(s2, 4); s2 += __shfl_xor(s2, 8);
        const float mu = s1 * (1.0f / 128.0f);
        const float rs = rsqrtf(s2 * (1.0f / 128.0f) - mu * mu + F_LNEPS);
        float* orow = xo + (size_t)n * 128;
        if (layer == 0) {
#pragma unroll
          for (int ct = 0; ct < 8; ++ct) {
            const float y = (vals[ct] - mu) * rs * g8[ct] + be8[ct];
            orow[16 * ct + lc] = y;
            bufB[n * ROWP + 16 * ct + lc] = f2bf(y);   // own-band x' stash
          }
        } else {
#pragma unroll
          for (int ct = 0; ct < 8; ++ct)
            orow[16 * ct + lc] = (vals[ct] - mu) * rs * g8[ct] + be8[ct];
        }
      }
    }
    __syncthreads();   // B6: layer boundary (buffers reused; xout -> next xsrc)
  }
}

extern "C" void kernel_launch(void* const* d_in, const int* in_sizes, int n_in,
                              void* d_out, int out_size, void* d_ws, size_t ws_size,
                              hipStream_t stream) {
  const float* G    = (const float*)d_in[0];
  const int*   msk  = (const int*)d_in[1];
  const float* r3   = (const float*)d_in[2];
  const float* swg  = (const float*)d_in[3];
  const float* Win  = (const float*)d_in[4];
  const float* bin  = (const float*)d_in[5];
  const float* Wout = (const float*)d_in[6];
  const float* bout = (const float*)d_in[7];
  const float* lng  = (const float*)d_in[8];
  const float* lnb  = (const float*)d_in[9];
  float* xout = (float*)d_out;

  const int B = in_sizes[0] / (128 * 128);
  const int nblk = B / 2;
  const bool ws_ok = ws_size >= (WTI_ELEMS + WTO_ELEMS) * sizeof(ushort_t);
  ushort_t* wtI = (ushort_t*)d_ws;
  ushort_t* wtO = wtI + WTI_ELEMS;

  if (ws_ok) {
    prep_weights<<<dim3(384), dim3(256), 0, stream>>>(Win, Wout, wtI, wtO);
    hipFuncSetAttribute(reinterpret_cast<const void*>(ngatt_dual<true>),
                        hipFuncAttributeMaxDynamicSharedMemorySize, LDS_BYTES);
    ngatt_dual<true><<<dim3(nblk), dim3(512), LDS_BYTES, stream>>>(
        G, msk, r3, swg, Win, bin, Wout, bout, lng, lnb, wtI, wtO, xout);
  } else {
    hipFuncSetAttribute(reinterpret_cast<const void*>(ngatt_dual<false>),
                        hipFuncAttributeMaxDynamicSharedMemorySize, LDS_BYTES);
    ngatt_dual<false><<<dim3(nblk), dim3(512), LDS_BYTES, stream>>>(
        G, msk, r3, swg, Win, bin, Wout, bout, lng, lnb, nullptr, nullptr, xout);
  }
}